// Round 13
// baseline (460.181 us; speedup 1.0000x reference)
//
#include <hip/hip_runtime.h>
#include <math.h>
#include <float.h>
#include <limits.h>

#define BNUM 2
#define V0 4096
#define V1N 1024
#define V2N 256
#define SUPN 7

typedef float float4v __attribute__((ext_vector_type(4)));
typedef float float2v __attribute__((ext_vector_type(2)));
typedef unsigned short ushort4v __attribute__((ext_vector_type(4)));
typedef unsigned short ushort8v __attribute__((ext_vector_type(8)));
typedef short short8v __attribute__((ext_vector_type(8)));
typedef __bf16 bf16x8 __attribute__((ext_vector_type(8)));
typedef unsigned long long u64;

__device__ __forceinline__ float fast_silu(float x){
  return __fdividef(x, 1.0f + __expf(-x));
}

// RNE float -> bf16
__device__ __forceinline__ unsigned short f2bf(float f){
  unsigned int u=__float_as_uint(f);
  u += 0x7FFFu + ((u>>16)&1u);
  return (unsigned short)(u>>16);
}
__device__ __forceinline__ float bf2f(unsigned short h){
  return __uint_as_float(((unsigned int)h)<<16);
}

// exact monotone float->uint transform
__device__ __forceinline__ unsigned int fkey(float f){
  unsigned int u = __float_as_uint(f);
  int m = ((int)u) >> 31;
  return u ^ (unsigned int)(m | 0x80000000);
}

__device__ __forceinline__ u64 shfl_xor_u64(u64 v, int m){
  unsigned int lo = (unsigned int)v, hi = (unsigned int)(v>>32);
  lo = (unsigned int)__shfl_xor((int)lo, m);
  hi = (unsigned int)__shfl_xor((int)hi, m);
  return ((u64)hi<<32) | lo;
}

// ---------------- fused column-normalize + stats zero ----------------
__global__ void colnorm_all_k(const float* __restrict__ d0, const float* __restrict__ dir1,
                              const float* __restrict__ dir2, const float* __restrict__ dir3,
                              const float* __restrict__ dir4,
                              float* __restrict__ cn0, float* __restrict__ cn1,
                              float* __restrict__ cn2, float* __restrict__ cn3,
                              float* __restrict__ cn4, float* __restrict__ stats){
  int c = blockIdx.x*256 + threadIdx.x;
  if(c < 1280) stats[c] = 0.0f;
  const float* s; float* o; int nc;
  if(c < 896){ s=d0; o=cn0; nc=896; }
  else if((c-=896) < 896){ s=dir1; o=cn1; nc=896; }
  else if((c-=896) < 1792){ s=dir2; o=cn2; nc=1792; }
  else if((c-=1792) < 1792){ s=dir3; o=cn3; nc=1792; }
  else { c-=1792; if(c>=3584) return; s=dir4; o=cn4; nc=3584; }
  float a=s[c], b=s[nc+c], e=s[2*nc+c];
  float n=sqrtf(a*a+b*b+e*e); n=fmaxf(n,1e-12f);
  o[c]=a/n; o[nc+c]=b/n; o[2*nc+c]=e/n;
}

// ---------------- self-KNN (k=10, skip self) ----------------
template<int VC, int THREADS, int MINW>
__global__ __launch_bounds__(THREADS, MINW) void knn10_k(const float* __restrict__ pts,
    int* __restrict__ out_idx, float* __restrict__ out_dirn)
{
  constexpr int CHUNK = VC/64;
  constexpr int QPB = THREADS/64;
  __shared__ float4v sp4[VC];
  __shared__ float sdd[QPB][34];
  __shared__ int   sdi[QPB][34];
  int t = threadIdx.x;
  int lane = t & 63;
  int wv   = t >> 6;
  int b = blockIdx.y;
  int j = blockIdx.x*QPB + wv;
  const float* pb = pts + (size_t)b*VC*3;
  for(int i=t; i<VC; i+=THREADS){
    float x=pb[3*i], y=pb[3*i+1], z=pb[3*i+2];
    float4v v; v[0]=x; v[1]=y; v[2]=z; v[3]=x*x+y*y+z*z;
    sp4[i]=v;
  }
  __syncthreads();
  float qx=pb[3*j], qy=pb[3*j+1], qz=pb[3*j+2];
  float qs=qx*qx+qy*qy+qz*qz;

  float dc[CHUNK];
  float p0=INFINITY, p1=INFINITY, p2=INFINITY, p3=INFINITY;
  #pragma unroll
  for(int c=0;c<CHUNK;c++){
    float4v p = sp4[c*64+lane];
    float dot = qx*p[0]+qy*p[1]+qz*p[2];
    float d = fmaf(-2.0f, dot, p[3]+qs);
    dc[c]=d;
    float s=d, a;
    a=fminf(p0,s); s=fmaxf(p0,s); p0=a;
    a=fminf(p1,s); s=fmaxf(p1,s); p1=a;
    a=fminf(p2,s); s=fmaxf(p2,s); p2=a;
    p3=fminf(p3,s);
  }

  float prev=-INFINITY;
  for(int sel=0; sel<11; ++sel){
    float cand = p0>prev ? p0 : (p1>prev ? p1 : (p2>prev ? p2 : (p3>prev ? p3 : INFINITY)));
    #pragma unroll
    for(int s=32;s;s>>=1) cand = fminf(cand, __shfl_xor(cand, s));
    prev=cand;
  }
  float v11 = prev;

  int cnt=0;
  #pragma unroll
  for(int c=0;c<CHUNK;c++){
    bool hit = dc[c] <= v11;
    u64 m = __ballot(hit);
    if(m){
      if(hit){
        int pos = cnt + __popcll(m & ((1ull<<lane)-1ull));
        if(pos<32){ sdd[wv][pos]=dc[c]; sdi[wv][pos]=c*64+lane; }
      }
      cnt += (int)__popcll(m);
    }
  }
  if(cnt>32) cnt=32;

  if(lane < cnt){
    float dl = sdd[wv][lane]; int il = sdi[wv][lane];
    int rank=0;
    for(int m2=0;m2<cnt;m2++){
      float dm=sdd[wv][m2]; int im=sdi[wv][m2];
      rank += (dm<dl || (dm==dl && im<il)) ? 1 : 0;
    }
    if(rank>=1 && rank<=10){
      size_t obase=((size_t)b*VC+j)*10 + (rank-1);
      out_idx[obase]=il;
      float4v p = sp4[il];
      float dx=p[0]-qx, dy=p[1]-qy, dz=p[2]-qz;
      float n=sqrtf(dx*dx+dy*dy+dz*dz); n=fmaxf(n,1e-12f);
      out_dirn[obase*3]=dx/n; out_dirn[obase*3+1]=dy/n; out_dirn[obase*3+2]=dz/n;
    }
  }
}

// ---------------- conv_surface + outer silu -> fm0 + out[:, :128] ----------------
template<int NODES>
__global__ __launch_bounds__(64*NODES) void conv_surf_k(
    const float* __restrict__ dirn, const float* __restrict__ cnd,
    float* __restrict__ fm0, float* __restrict__ outbuf)
{
  int tid=threadIdx.x, nd=tid>>6, t=tid&63;
  int b=blockIdx.y, i=blockIdx.x*NODES+nd;
  __shared__ float sd[NODES][32];
  if(t<30) sd[nd][t]=dirn[((size_t)(b*V0+i))*30+t];
  __syncthreads();
  float acc0=0.0f, acc1=0.0f;
  for(int s=0;s<SUPN;s++){
    int col=s*128+t;
    float wa0=cnd[col],     wa1=cnd[896+col],     wa2=cnd[1792+col];
    float wb0=cnd[col+64],  wb1=cnd[896+col+64],  wb2=cnd[1792+col+64];
    float m0=-INFINITY, m1=-INFINITY;
    #pragma unroll
    for(int n=0;n<10;n++){
      float dx=sd[nd][3*n], dy=sd[nd][3*n+1], dz=sd[nd][3*n+2];
      m0=fmaxf(m0, fast_silu(dx*wa0+dy*wa1+dz*wa2));
      m1=fmaxf(m1, fast_silu(dx*wb0+dy*wb1+dz*wb2));
    }
    acc0+=m0; acc1+=m1;
  }
  float r0=fast_silu(acc0), r1=fast_silu(acc1);
  size_t frow=(size_t)(b*V0+i)*128;
  fm0[frow+t]=r0; fm0[frow+64+t]=r1;
  size_t orow=(size_t)(b*V0+i)*1280;
  outbuf[orow+t]=r0; outbuf[orow+64+t]=r1;
}

// ---------------- MFMA GEMM, bf16x2-split (hi/lo), split epilogue ----------------
// x = hi + lo (both bf16); D = Ah*Bh + Ah*Bl + Al*Bh accumulated in fp32 MFMA.
// LDS rows padded to 56 ushorts (112B = 28 dwords): fragment-read banks have
// period 8 in fr -> 2-way conflict (free, m136); was 48 (24 dwords, period 4
// -> 4-way, 1.58x). 112B is 16B-multiple so all 16B accesses stay aligned.
__global__ __launch_bounds__(256) void gemm_mfma_k(
    const float* __restrict__ A, const float* __restrict__ W,
    const float* __restrict__ bias,
    float* __restrict__ Cc, unsigned short* __restrict__ Sp,
    int M, int N, int K, int outC)
{
  __shared__ __attribute__((aligned(16))) unsigned short Ah[128][56];
  __shared__ __attribute__((aligned(16))) unsigned short Al[128][56];
  __shared__ __attribute__((aligned(16))) unsigned short Bh[128][56];
  __shared__ __attribute__((aligned(16))) unsigned short Bl[128][56];
  int t=threadIdx.x;
  int lane=t&63, wv=t>>6;
  int wr=(wv>>1)*64, wc=(wv&1)*64;
  int bm=blockIdx.y*128, bn=blockIdx.x*128;

  float4v acc[4][4];
  #pragma unroll
  for(int fi=0;fi<4;fi++)
    #pragma unroll
    for(int fj=0;fj<4;fj++) acc[fi][fj]=(float4v)(0.0f);

  // A staging: thread covers row ar, k-quads (af..af+3) => k in [af*4, af*4+16)
  int ar=t>>1, af=(t&1)*4;
  const float* Ag = A + (size_t)(bm+ar)*K + af*4;
  // B staging: two tasks, col nn, k-blocks kb0 and kb0+2 (8 k's each)
  int nn=t&127, kb0=t>>7;
  const float* Wg = W + bn + nn;

  float4v pa[4];
  float pb[2][8];
  #pragma unroll
  for(int q=0;q<4;q++) pa[q]=*(const float4v*)(Ag + q*4);
  #pragma unroll
  for(int j=0;j<8;j++){
    pb[0][j]=Wg[(size_t)(kb0*8+j)*N];
    pb[1][j]=Wg[(size_t)((kb0+2)*8+j)*N];
  }

  for(int k0=0;k0<K;k0+=32){
    __syncthreads();
    // convert + stage
    #pragma unroll
    for(int q=0;q<4;q++){
      ushort4v hv, lv;
      #pragma unroll
      for(int i2=0;i2<4;i2++){
        float x=pa[q][i2];
        unsigned short h=f2bf(x);
        hv[i2]=h;
        lv[i2]=f2bf(x - bf2f(h));
      }
      *(ushort4v*)&Ah[ar][(af+q)*4]=hv;
      *(ushort4v*)&Al[ar][(af+q)*4]=lv;
    }
    #pragma unroll
    for(int task=0;task<2;task++){
      int kb=kb0+task*2;
      ushort8v hv, lv;
      #pragma unroll
      for(int j=0;j<8;j++){
        float x=pb[task][j];
        unsigned short h=f2bf(x);
        hv[j]=h;
        lv[j]=f2bf(x - bf2f(h));
      }
      *(ushort8v*)&Bh[nn][kb*8]=hv;
      *(ushort8v*)&Bl[nn][kb*8]=lv;
    }
    __syncthreads();
    // prefetch next K-step
    if(k0+32<K){
      #pragma unroll
      for(int q=0;q<4;q++) pa[q]=*(const float4v*)(Ag + k0+32 + q*4);
      #pragma unroll
      for(int j=0;j<8;j++){
        pb[0][j]=Wg[(size_t)(k0+32+kb0*8+j)*N];
        pb[1][j]=Wg[(size_t)(k0+32+(kb0+2)*8+j)*N];
      }
    }
    // compute
    int fr=lane&15;
    int koff=(lane>>4)*8;
    union { short8v s; bf16x8 b; } Bfh[4], Bfl[4];
    #pragma unroll
    for(int fj=0;fj<4;fj++){
      Bfh[fj].s = *(const short8v*)&Bh[wc+fj*16+fr][koff];
      Bfl[fj].s = *(const short8v*)&Bl[wc+fj*16+fr][koff];
    }
    #pragma unroll
    for(int fi=0;fi<4;fi++){
      union { short8v s; bf16x8 b; } Afh, Afl;
      Afh.s = *(const short8v*)&Ah[wr+fi*16+fr][koff];
      Afl.s = *(const short8v*)&Al[wr+fi*16+fr][koff];
      #pragma unroll
      for(int fj=0;fj<4;fj++){
        acc[fi][fj] = __builtin_amdgcn_mfma_f32_16x16x32_bf16(Afh.b, Bfh[fj].b, acc[fi][fj], 0,0,0);
        acc[fi][fj] = __builtin_amdgcn_mfma_f32_16x16x32_bf16(Afh.b, Bfl[fj].b, acc[fi][fj], 0,0,0);
        acc[fi][fj] = __builtin_amdgcn_mfma_f32_16x16x32_bf16(Afl.b, Bfh[fj].b, acc[fi][fj], 0,0,0);
      }
    }
  }

  // epilogue: D[row=(lane>>4)*4+reg][col=lane&15] per frag
  int fr=lane&15, r0=(lane>>4)*4;
  float bb4[4];
  #pragma unroll
  for(int fj=0;fj<4;fj++) bb4[fj]=bias[bn+wc+fj*16+fr];
  if(bn+128<=outC){
    #pragma unroll
    for(int fi=0;fi<4;fi++)
      #pragma unroll
      for(int fj=0;fj<4;fj++)
        #pragma unroll
        for(int rg=0;rg<4;rg++){
          size_t row=(size_t)(bm+wr+fi*16+r0+rg);
          Cc[row*outC + bn+wc+fj*16+fr]=acc[fi][fj][rg]+bb4[fj];
        }
  } else {
    int sw=7*outC, scol=bn-outC;
    #pragma unroll
    for(int fi=0;fi<4;fi++)
      #pragma unroll
      for(int fj=0;fj<4;fj++)
        #pragma unroll
        for(int rg=0;rg<4;rg++){
          size_t row=(size_t)(bm+wr+fi*16+r0+rg);
          Sp[row*sw + scol+wc+fj*16+fr]=f2bf(acc[fi][fj][rg]+bb4[fj]);
        }
  }
}

// ---------------- conv_layer aggregate (bf16 support gather) + BN-stats ----------------
// Round-3 version (best measured across 6 structural variants: ~68us @ C=128).
// Do not restructure (rounds 2/4/5/8 all regressed).
template<int C, int TPN, int NODES>
__global__ __launch_bounds__(TPN*NODES) void conv_agg_k(
    const float* __restrict__ cent, const unsigned short* __restrict__ sup,
    int Vb,
    const float* __restrict__ dirn, const int* __restrict__ nbidx,
    const float* __restrict__ cnd,
    float* __restrict__ outp, float* __restrict__ stats)
{
  constexpr int ncol = SUPN*C;
  constexpr int NT = TPN*NODES;
  int tid=threadIdx.x, nd=tid/TPN, t=tid%TPN;
  int b=blockIdx.y, i=blockIdx.x*NODES+nd;
  __shared__ float sd[NODES][32];
  __shared__ int snb[NODES][12];
  __shared__ float ssum[C], ssq[C];
  __shared__ float scn[3*ncol];
  if(t<30) sd[nd][t]=dirn[((size_t)(b*Vb+i))*30+t];
  if(t<10) snb[nd][t]=nbidx[(size_t)(b*Vb+i)*10+t];
  for(int c=tid;c<3*ncol;c+=NT) scn[c]=cnd[c];
  if(stats) for(int c=tid;c<C;c+=NT){ ssum[c]=0.0f; ssq[c]=0.0f; }
  __syncthreads();

  const int col0 = t*4;
  const unsigned short* fb = sup + (size_t)b*Vb*ncol;

  float m[SUPN][4];
  #pragma unroll
  for(int s=0;s<SUPN;s++)
    #pragma unroll
    for(int v=0;v<4;v++) m[s][v]=-INFINITY;

  ushort4v bufA[SUPN], bufB[SUPN];
  float dax,day,daz, dbx,dby,dbz;
  {
    unsigned int off=(unsigned int)snb[nd][0]*ncol + col0;
    #pragma unroll
    for(int s=0;s<SUPN;s++) bufA[s]=*(const ushort4v*)&fb[off + s*C];
    dax=sd[nd][0]; day=sd[nd][1]; daz=sd[nd][2];
  }
  #pragma unroll 1
  for(int np=0;np<5;np++){
    {
      int nn=2*np+1;
      unsigned int off=(unsigned int)snb[nd][nn]*ncol + col0;
      #pragma unroll
      for(int s=0;s<SUPN;s++) bufB[s]=*(const ushort4v*)&fb[off + s*C];
      dbx=sd[nd][3*nn]; dby=sd[nd][3*nn+1]; dbz=sd[nd][3*nn+2];
    }
    #pragma unroll
    for(int s=0;s<SUPN;s++){
      int cb=s*C+col0;
      float4v w0=*(const float4v*)&scn[cb];
      float4v w1=*(const float4v*)&scn[ncol+cb];
      float4v w2=*(const float4v*)&scn[2*ncol+cb];
      ushort4v sv=bufA[s];
      #pragma unroll
      for(int v=0;v<4;v++){
        float d = dax*w0[v] + day*w1[v] + daz*w2[v];
        m[s][v] = fmaxf(m[s][v], fast_silu(d)*bf2f(sv[v]));
      }
    }
    if(np<4){
      int nn=2*np+2;
      unsigned int off=(unsigned int)snb[nd][nn]*ncol + col0;
      #pragma unroll
      for(int s=0;s<SUPN;s++) bufA[s]=*(const ushort4v*)&fb[off + s*C];
      dax=sd[nd][3*nn]; day=sd[nd][3*nn+1]; daz=sd[nd][3*nn+2];
    }
    #pragma unroll
    for(int s=0;s<SUPN;s++){
      int cb=s*C+col0;
      float4v w0=*(const float4v*)&scn[cb];
      float4v w1=*(const float4v*)&scn[ncol+cb];
      float4v w2=*(const float4v*)&scn[2*ncol+cb];
      ushort4v sv=bufB[s];
      #pragma unroll
      for(int v=0;v<4;v++){
        float d = dbx*w0[v] + dby*w1[v] + dbz*w2[v];
        m[s][v] = fmaxf(m[s][v], fast_silu(d)*bf2f(sv[v]));
      }
    }
  }

  float acc[4];
  {
    float4v cv=*(const float4v*)&cent[(size_t)(b*Vb+i)*C + col0];
    #pragma unroll
    for(int v=0;v<4;v++){
      acc[v]=cv[v];
      #pragma unroll
      for(int s=0;s<SUPN;s++) acc[v]+=m[s][v];
    }
  }
  {
    float4v ov;
    #pragma unroll
    for(int v=0;v<4;v++) ov[v]=acc[v];
    *(float4v*)&outp[(size_t)(b*Vb+i)*C + col0]=ov;
  }
  if(stats){
    #pragma unroll
    for(int v=0;v<4;v++){
      atomicAdd(&ssum[col0+v], acc[v]);
      atomicAdd(&ssq[col0+v], acc[v]*acc[v]);
    }
    __syncthreads();
    for(int c=tid;c<C;c+=NT){
      atomicAdd(&stats[c], ssum[c]);
      atomicAdd(&stats[C+c], ssq[c]);
    }
  }
}

// ---------------- BN apply + silu, float4 (+ optional out-slice write) ----------------
__global__ void bn_silu_k(const float* __restrict__ xin, const float* __restrict__ sums,
                          float invM, int C, const float* __restrict__ g, const float* __restrict__ bb,
                          float* __restrict__ y, int nquad, float* __restrict__ osl, int cshift)
{
  int gid=blockIdx.x*blockDim.x+threadIdx.x;
  if(gid>=nquad) return;
  int base=gid*4;
  int c=base&(C-1);
  float4v xv=*(const float4v*)&xin[base];
  float4v sm=*(const float4v*)&sums[c];
  float4v sq=*(const float4v*)&sums[C+c];
  float4v gv=*(const float4v*)&g[c];
  float4v bv=*(const float4v*)&bb[c];
  float4v r;
  #pragma unroll
  for(int u=0;u<4;u++){
    float mean=sm[u]*invM;
    float var=sq[u]*invM - mean*mean;
    float v=(xv[u]-mean)*rsqrtf(var+1e-5f)*gv[u]+bv[u];
    r[u]=fast_silu(v);
  }
  *(float4v*)&y[base]=r;
  if(osl){
    int row=base>>cshift;
    *(float4v*)&osl[(size_t)row*1280 + c]=r;
  }
}

// ---------------- pool over first-4 of idx10 at perm rows + coord gather ----
template<int C, int NODES>
__global__ __launch_bounds__((C/4)*NODES) void pool_gather_k(
    const float* __restrict__ fm, int Vsrc,
    const int* __restrict__ idx10, const int* __restrict__ perm,
    const float* __restrict__ vsrc,
    float* __restrict__ fout, float* __restrict__ vout, int Vq)
{
  constexpr int TPN=C/4;
  int tid=threadIdx.x, nd=tid/TPN, t=tid%TPN;
  int b=blockIdx.y, j=blockIdx.x*NODES+nd;
  int r=perm[j];
  const int* id=idx10+((size_t)b*Vsrc+r)*10;
  const float* fb=fm+(size_t)b*Vsrc*C;
  float4v m=(float4v)(-INFINITY);
  #pragma unroll
  for(int n=0;n<4;n++){
    float4v fv=*(const float4v*)&fb[(size_t)id[n]*C + t*4];
    #pragma unroll
    for(int u=0;u<4;u++) m[u]=fmaxf(m[u],fv[u]);
  }
  *(float4v*)&fout[(size_t)(b*Vq+j)*C + t*4]=m;
  if(t<3) vout[((size_t)b*Vq+j)*3+t]=vsrc[((size_t)b*Vsrc+r)*3+t];
}

// ---------------- fused nearest (v1,v2) + upsample concat ----------------
__global__ __launch_bounds__(512) void nearest_concat_k(
    const float* __restrict__ v1, const float* __restrict__ v2,
    const float* __restrict__ x,
    const float* __restrict__ fm2, const float* __restrict__ fm3,
    const float* __restrict__ fm4,
    float* __restrict__ outp)
{
  __shared__ float4v s1[V1N];
  __shared__ float4v s2[V2N];
  int t=threadIdx.x;
  int lane=t&63, wv=t>>6;
  int b=blockIdx.y; int j=blockIdx.x*8+wv;
  const float* c1=v1+(size_t)b*V1N*3;
  const float* c2=v2+(size_t)b*V2N*3;
  for(int i=t;i<V1N;i+=512){
    float xx=c1[3*i],yy=c1[3*i+1],zz=c1[3*i+2];
    float4v v; v[0]=xx;v[1]=yy;v[2]=zz;v[3]=xx*xx+yy*yy+zz*zz; s1[i]=v;
  }
  for(int i=t;i<V2N;i+=512){
    float xx=c2[3*i],yy=c2[3*i+1],zz=c2[3*i+2];
    float4v v; v[0]=xx;v[1]=yy;v[2]=zz;v[3]=xx*xx+yy*yy+zz*zz; s2[i]=v;
  }
  __syncthreads();
  const float* qb=x+(size_t)b*V0*3;
  float qx=qb[3*j],qy=qb[3*j+1],qz=qb[3*j+2];
  float qs=qx*qx+qy*qy+qz*qz;
  u64 bk=~0ull;
  #pragma unroll 4
  for(int c=0;c<V1N/64;c++){
    int i=c*64+lane;
    float4v p=s1[i];
    float dot=qx*p[0]+qy*p[1]+qz*p[2];
    float d=fmaf(-2.0f,dot,p[3]+qs);
    u64 k=((u64)fkey(d)<<32)|(unsigned int)i;
    bk = k<bk ? k : bk;
  }
  #pragma unroll
  for(int s=32;s;s>>=1){ u64 o=shfl_xor_u64(bk,s); bk = o<bk?o:bk; }
  int j1=(int)(bk&0xffffffffu);
  bk=~0ull;
  #pragma unroll 4
  for(int c=0;c<V2N/64;c++){
    int i=c*64+lane;
    float4v p=s2[i];
    float dot=qx*p[0]+qy*p[1]+qz*p[2];
    float d=fmaf(-2.0f,dot,p[3]+qs);
    u64 k=((u64)fkey(d)<<32)|(unsigned int)i;
    bk = k<bk ? k : bk;
  }
  #pragma unroll
  for(int s=32;s;s>>=1){ u64 o=shfl_xor_u64(bk,s); bk = o<bk?o:bk; }
  int j2=(int)(bk&0xffffffffu);

  const float4v* f2p=(const float4v*)(fm2 + ((size_t)b*V1N+j1)*256);
  const float4v* f3p=(const float4v*)(fm3 + ((size_t)b*V1N+j1)*256);
  const float4v* f4p=(const float4v*)(fm4 + ((size_t)b*V2N+j2)*512);
  float4v* op=(float4v*)(outp + (size_t)(b*V0+j)*1280) + 64;
  op[lane]       = f2p[lane];
  op[64+lane]    = f3p[lane];
  op[128+lane]   = f4p[lane];
  op[192+lane]   = f4p[64+lane];
}

extern "C" void kernel_launch(void* const* d_in, const int* in_sizes, int n_in,
                              void* d_out, int out_size, void* d_ws, size_t ws_size,
                              hipStream_t stream) {
  const float* x   =(const float*)d_in[0];
  const float* d0  =(const float*)d_in[1];
  const float* w1  =(const float*)d_in[2];
  const float* b1  =(const float*)d_in[3];
  const float* dir1=(const float*)d_in[4];
  const float* g1  =(const float*)d_in[5];
  const float* bb1 =(const float*)d_in[6];
  const float* w2  =(const float*)d_in[7];
  const float* b2  =(const float*)d_in[8];
  const float* dir2=(const float*)d_in[9];
  const float* g2  =(const float*)d_in[10];
  const float* bb2 =(const float*)d_in[11];
  const float* w3  =(const float*)d_in[12];
  const float* b3  =(const float*)d_in[13];
  const float* dir3=(const float*)d_in[14];
  const float* g3  =(const float*)d_in[15];
  const float* bb3 =(const float*)d_in[16];
  const float* w4  =(const float*)d_in[17];
  const float* b4  =(const float*)d_in[18];
  const float* dir4=(const float*)d_in[19];
  const int* perm1 =(const int*)d_in[20];
  const int* perm2 =(const int*)d_in[21];
  float* out=(float*)d_out;

  float* w=(float*)d_ws;
  size_t off=0;
  auto alloc=[&](size_t n){ float* p=w+off; off+=n; return p; };
  float* cn0 =alloc(2688);
  float* cn1 =alloc(2688);
  float* cn2 =alloc(5376);
  float* cn3 =alloc(5376);
  float* cn4 =alloc(10752);
  float* dirnx =alloc((size_t)BNUM*V0*30);
  float* dirnv1=alloc((size_t)BNUM*V1N*30);
  float* dirnv2=alloc((size_t)BNUM*V2N*30);
  float* fm0 =alloc((size_t)BNUM*V0*128);
  float* cent=alloc((size_t)BNUM*V0*128);
  unsigned short* supb=(unsigned short*)alloc((size_t)BNUM*V0*896/2);
  float* fm1r=alloc((size_t)BNUM*V0*128);
  float* fm1 =alloc((size_t)BNUM*V0*128);
  float* f1  =alloc((size_t)BNUM*V1N*128);
  float* v1  =alloc((size_t)BNUM*V1N*3);
  float* fm2r=alloc((size_t)BNUM*V1N*256);
  float* fm2 =alloc((size_t)BNUM*V1N*256);
  float* fm3r=alloc((size_t)BNUM*V1N*256);
  float* fm3 =alloc((size_t)BNUM*V1N*256);
  float* f2  =alloc((size_t)BNUM*V2N*256);
  float* v2  =alloc((size_t)BNUM*V2N*3);
  float* fm4 =alloc((size_t)BNUM*V2N*512);
  float* stats=alloc(1280);
  int* idx10x =(int*)alloc((size_t)BNUM*V0*10);
  int* idx10v1=(int*)alloc((size_t)BNUM*V1N*10);
  int* idx10v2=(int*)alloc((size_t)BNUM*V2N*10);

  colnorm_all_k<<<dim3(35),256,0,stream>>>(d0,dir1,dir2,dir3,dir4,cn0,cn1,cn2,cn3,cn4,stats);

  // knn10 on x
  knn10_k<V0,1024,4><<<dim3(V0/16,BNUM),1024,0,stream>>>(x, idx10x, dirnx);
  // fm0 = silu(conv_surface) -> fm0 scratch + out[:, :128]
  conv_surf_k<4><<<dim3(V0/4,BNUM),256,0,stream>>>(dirnx, cn0, fm0, out);

  // layer 1 (C=128): GEMM 8192x1024x128
  gemm_mfma_k<<<dim3(1024/128,(BNUM*V0)/128),256,0,stream>>>(fm0, w1, b1, cent, supb, BNUM*V0, 1024, 128, 128);
  conv_agg_k<128,32,8><<<dim3(V0/8,BNUM),256,0,stream>>>(cent, supb, V0, dirnx, idx10x, cn1, fm1r, stats);
  bn_silu_k<<<dim3((BNUM*V0*128/4)/256),256,0,stream>>>(fm1r, stats, 1.0f/(BNUM*V0), 128, g1, bb1, fm1, BNUM*V0*128/4, out+128, 7);

  // pool (first-4 of idx10x at perm1) + v1 gather
  pool_gather_k<128,8><<<dim3(V1N/8,BNUM),256,0,stream>>>(fm1, V0, idx10x, perm1, x, f1, v1, V1N);

  // knn10 on v1
  knn10_k<V1N,256,6><<<dim3(V1N/4,BNUM),256,0,stream>>>(v1, idx10v1, dirnv1);

  // layer 2 (C=256): GEMM 2048x2048x128
  gemm_mfma_k<<<dim3(2048/128,(BNUM*V1N)/128),256,0,stream>>>(f1, w2, b2, cent, supb, BNUM*V1N, 2048, 128, 256);
  conv_agg_k<256,64,4><<<dim3(V1N/4,BNUM),256,0,stream>>>(cent, supb, V1N, dirnv1, idx10v1, cn2, fm2r, stats+256);
  bn_silu_k<<<dim3((BNUM*V1N*256/4)/256),256,0,stream>>>(fm2r, stats+256, 1.0f/(BNUM*V1N), 256, g2, bb2, fm2, BNUM*V1N*256/4, nullptr, 8);

  // layer 3 (C=256): GEMM 2048x2048x256
  gemm_mfma_k<<<dim3(2048/128,(BNUM*V1N)/128),256,0,stream>>>(fm2, w3, b3, cent, supb, BNUM*V1N, 2048, 256, 256);
  conv_agg_k<256,64,4><<<dim3(V1N/4,BNUM),256,0,stream>>>(cent, supb, V1N, dirnv1, idx10v1, cn3, fm3r, stats+768);
  bn_silu_k<<<dim3((BNUM*V1N*256/4)/256),256,0,stream>>>(fm3r, stats+768, 1.0f/(BNUM*V1N), 256, g3, bb3, fm3, BNUM*V1N*256/4, nullptr, 8);

  // pool (first-4 of idx10v1 at perm2) + v2 gather
  pool_gather_k<256,4><<<dim3(V2N/4,BNUM),256,0,stream>>>(fm3, V1N, idx10v1, perm2, v1, f2, v2, V2N);

  // knn10 on v2
  knn10_k<V2N,256,6><<<dim3(V2N/4,BNUM),256,0,stream>>>(v2, idx10v2, dirnv2);

  // layer 4 (C=512): GEMM 512x4096x256, no bn/silu
  gemm_mfma_k<<<dim3(4096/128,(BNUM*V2N)/128),256,0,stream>>>(f2, w4, b4, cent, supb, BNUM*V2N, 4096, 256, 512);
  conv_agg_k<512,128,2><<<dim3(V2N/2,BNUM),256,0,stream>>>(cent, supb, V2N, dirnv2, idx10v2, cn4, fm4, nullptr);

  // fused nearest + upsample concat
  nearest_concat_k<<<dim3(V0/8,BNUM),512,0,stream>>>(v1, v2, x, fm2, fm3, fm4, out);
}

// Round 14
// 454.747 us; speedup vs baseline: 1.0120x; 1.0120x over previous
//
#include <hip/hip_runtime.h>
#include <math.h>
#include <float.h>
#include <limits.h>

#define BNUM 2
#define V0 4096
#define V1N 1024
#define V2N 256
#define SUPN 7

typedef float float4v __attribute__((ext_vector_type(4)));
typedef float float2v __attribute__((ext_vector_type(2)));
typedef unsigned short ushort4v __attribute__((ext_vector_type(4)));
typedef unsigned short ushort8v __attribute__((ext_vector_type(8)));
typedef short short8v __attribute__((ext_vector_type(8)));
typedef __bf16 bf16x8 __attribute__((ext_vector_type(8)));
typedef unsigned long long u64;

__device__ __forceinline__ float fast_silu(float x){
  return __fdividef(x, 1.0f + __expf(-x));
}

// RNE float -> bf16
__device__ __forceinline__ unsigned short f2bf(float f){
  unsigned int u=__float_as_uint(f);
  u += 0x7FFFu + ((u>>16)&1u);
  return (unsigned short)(u>>16);
}
__device__ __forceinline__ float bf2f(unsigned short h){
  return __uint_as_float(((unsigned int)h)<<16);
}

// exact monotone float->uint transform
__device__ __forceinline__ unsigned int fkey(float f){
  unsigned int u = __float_as_uint(f);
  int m = ((int)u) >> 31;
  return u ^ (unsigned int)(m | 0x80000000);
}

__device__ __forceinline__ u64 shfl_xor_u64(u64 v, int m){
  unsigned int lo = (unsigned int)v, hi = (unsigned int)(v>>32);
  lo = (unsigned int)__shfl_xor((int)lo, m);
  hi = (unsigned int)__shfl_xor((int)hi, m);
  return ((u64)hi<<32) | lo;
}

// ---------------- fused column-normalize + stats zero ----------------
__global__ void colnorm_all_k(const float* __restrict__ d0, const float* __restrict__ dir1,
                              const float* __restrict__ dir2, const float* __restrict__ dir3,
                              const float* __restrict__ dir4,
                              float* __restrict__ cn0, float* __restrict__ cn1,
                              float* __restrict__ cn2, float* __restrict__ cn3,
                              float* __restrict__ cn4, float* __restrict__ stats){
  int c = blockIdx.x*256 + threadIdx.x;
  if(c < 1280) stats[c] = 0.0f;
  const float* s; float* o; int nc;
  if(c < 896){ s=d0; o=cn0; nc=896; }
  else if((c-=896) < 896){ s=dir1; o=cn1; nc=896; }
  else if((c-=896) < 1792){ s=dir2; o=cn2; nc=1792; }
  else if((c-=1792) < 1792){ s=dir3; o=cn3; nc=1792; }
  else { c-=1792; if(c>=3584) return; s=dir4; o=cn4; nc=3584; }
  float a=s[c], b=s[nc+c], e=s[2*nc+c];
  float n=sqrtf(a*a+b*b+e*e); n=fmaxf(n,1e-12f);
  o[c]=a/n; o[nc+c]=b/n; o[2*nc+c]=e/n;
}

// ---------------- self-KNN (k=10, skip self) ----------------
template<int VC, int THREADS, int MINW>
__global__ __launch_bounds__(THREADS, MINW) void knn10_k(const float* __restrict__ pts,
    int* __restrict__ out_idx, float* __restrict__ out_dirn)
{
  constexpr int CHUNK = VC/64;
  constexpr int QPB = THREADS/64;
  __shared__ float4v sp4[VC];
  __shared__ float sdd[QPB][34];
  __shared__ int   sdi[QPB][34];
  int t = threadIdx.x;
  int lane = t & 63;
  int wv   = t >> 6;
  int b = blockIdx.y;
  int j = blockIdx.x*QPB + wv;
  const float* pb = pts + (size_t)b*VC*3;
  for(int i=t; i<VC; i+=THREADS){
    float x=pb[3*i], y=pb[3*i+1], z=pb[3*i+2];
    float4v v; v[0]=x; v[1]=y; v[2]=z; v[3]=x*x+y*y+z*z;
    sp4[i]=v;
  }
  __syncthreads();
  float qx=pb[3*j], qy=pb[3*j+1], qz=pb[3*j+2];
  float qs=qx*qx+qy*qy+qz*qz;

  float dc[CHUNK];
  float p0=INFINITY, p1=INFINITY, p2=INFINITY, p3=INFINITY;
  #pragma unroll
  for(int c=0;c<CHUNK;c++){
    float4v p = sp4[c*64+lane];
    float dot = qx*p[0]+qy*p[1]+qz*p[2];
    float d = fmaf(-2.0f, dot, p[3]+qs);
    dc[c]=d;
    float s=d, a;
    a=fminf(p0,s); s=fmaxf(p0,s); p0=a;
    a=fminf(p1,s); s=fmaxf(p1,s); p1=a;
    a=fminf(p2,s); s=fmaxf(p2,s); p2=a;
    p3=fminf(p3,s);
  }

  float prev=-INFINITY;
  for(int sel=0; sel<11; ++sel){
    float cand = p0>prev ? p0 : (p1>prev ? p1 : (p2>prev ? p2 : (p3>prev ? p3 : INFINITY)));
    #pragma unroll
    for(int s=32;s;s>>=1) cand = fminf(cand, __shfl_xor(cand, s));
    prev=cand;
  }
  float v11 = prev;

  int cnt=0;
  #pragma unroll
  for(int c=0;c<CHUNK;c++){
    bool hit = dc[c] <= v11;
    u64 m = __ballot(hit);
    if(m){
      if(hit){
        int pos = cnt + __popcll(m & ((1ull<<lane)-1ull));
        if(pos<32){ sdd[wv][pos]=dc[c]; sdi[wv][pos]=c*64+lane; }
      }
      cnt += (int)__popcll(m);
    }
  }
  if(cnt>32) cnt=32;

  if(lane < cnt){
    float dl = sdd[wv][lane]; int il = sdi[wv][lane];
    int rank=0;
    for(int m2=0;m2<cnt;m2++){
      float dm=sdd[wv][m2]; int im=sdi[wv][m2];
      rank += (dm<dl || (dm==dl && im<il)) ? 1 : 0;
    }
    if(rank>=1 && rank<=10){
      size_t obase=((size_t)b*VC+j)*10 + (rank-1);
      out_idx[obase]=il;
      float4v p = sp4[il];
      float dx=p[0]-qx, dy=p[1]-qy, dz=p[2]-qz;
      float n=sqrtf(dx*dx+dy*dy+dz*dz); n=fmaxf(n,1e-12f);
      out_dirn[obase*3]=dx/n; out_dirn[obase*3+1]=dy/n; out_dirn[obase*3+2]=dz/n;
    }
  }
}

// ---------------- conv_surface + outer silu -> fm0 + out[:, :128] ----------------
template<int NODES>
__global__ __launch_bounds__(64*NODES) void conv_surf_k(
    const float* __restrict__ dirn, const float* __restrict__ cnd,
    float* __restrict__ fm0, float* __restrict__ outbuf)
{
  int tid=threadIdx.x, nd=tid>>6, t=tid&63;
  int b=blockIdx.y, i=blockIdx.x*NODES+nd;
  __shared__ float sd[NODES][32];
  if(t<30) sd[nd][t]=dirn[((size_t)(b*V0+i))*30+t];
  __syncthreads();
  float acc0=0.0f, acc1=0.0f;
  for(int s=0;s<SUPN;s++){
    int col=s*128+t;
    float wa0=cnd[col],     wa1=cnd[896+col],     wa2=cnd[1792+col];
    float wb0=cnd[col+64],  wb1=cnd[896+col+64],  wb2=cnd[1792+col+64];
    float m0=-INFINITY, m1=-INFINITY;
    #pragma unroll
    for(int n=0;n<10;n++){
      float dx=sd[nd][3*n], dy=sd[nd][3*n+1], dz=sd[nd][3*n+2];
      m0=fmaxf(m0, fast_silu(dx*wa0+dy*wa1+dz*wa2));
      m1=fmaxf(m1, fast_silu(dx*wb0+dy*wb1+dz*wb2));
    }
    acc0+=m0; acc1+=m1;
  }
  float r0=fast_silu(acc0), r1=fast_silu(acc1);
  size_t frow=(size_t)(b*V0+i)*128;
  fm0[frow+t]=r0; fm0[frow+64+t]=r1;
  size_t orow=(size_t)(b*V0+i)*1280;
  outbuf[orow+t]=r0; outbuf[orow+64+t]=r1;
}

// ---------------- MFMA GEMM, bf16x2-split (hi/lo), split epilogue ----------------
// x = hi + lo (both bf16); D = Ah*Bh + Ah*Bl + Al*Bh accumulated in fp32 MFMA.
// LDS [128][48] ushort (48KB total -> 3 blocks/CU; the 56-pad variant fixed a
// 4-way read conflict but dropped to 2 blocks/CU and regressed — round 13).
__global__ __launch_bounds__(256) void gemm_mfma_k(
    const float* __restrict__ A, const float* __restrict__ W,
    const float* __restrict__ bias,
    float* __restrict__ Cc, unsigned short* __restrict__ Sp,
    int M, int N, int K, int outC)
{
  __shared__ __attribute__((aligned(16))) unsigned short Ah[128][48];
  __shared__ __attribute__((aligned(16))) unsigned short Al[128][48];
  __shared__ __attribute__((aligned(16))) unsigned short Bh[128][48];
  __shared__ __attribute__((aligned(16))) unsigned short Bl[128][48];
  int t=threadIdx.x;
  int lane=t&63, wv=t>>6;
  int wr=(wv>>1)*64, wc=(wv&1)*64;
  int bm=blockIdx.y*128, bn=blockIdx.x*128;

  float4v acc[4][4];
  #pragma unroll
  for(int fi=0;fi<4;fi++)
    #pragma unroll
    for(int fj=0;fj<4;fj++) acc[fi][fj]=(float4v)(0.0f);

  // A staging: thread covers row ar, k-quads (af..af+3) => k in [af*4, af*4+16)
  int ar=t>>1, af=(t&1)*4;
  const float* Ag = A + (size_t)(bm+ar)*K + af*4;
  // B staging: two tasks, col nn, k-blocks kb0 and kb0+2 (8 k's each)
  int nn=t&127, kb0=t>>7;
  const float* Wg = W + bn + nn;

  float4v pa[4];
  float pb[2][8];
  #pragma unroll
  for(int q=0;q<4;q++) pa[q]=*(const float4v*)(Ag + q*4);
  #pragma unroll
  for(int j=0;j<8;j++){
    pb[0][j]=Wg[(size_t)(kb0*8+j)*N];
    pb[1][j]=Wg[(size_t)((kb0+2)*8+j)*N];
  }

  for(int k0=0;k0<K;k0+=32){
    __syncthreads();
    // convert + stage
    #pragma unroll
    for(int q=0;q<4;q++){
      ushort4v hv, lv;
      #pragma unroll
      for(int i2=0;i2<4;i2++){
        float x=pa[q][i2];
        unsigned short h=f2bf(x);
        hv[i2]=h;
        lv[i2]=f2bf(x - bf2f(h));
      }
      *(ushort4v*)&Ah[ar][(af+q)*4]=hv;
      *(ushort4v*)&Al[ar][(af+q)*4]=lv;
    }
    #pragma unroll
    for(int task=0;task<2;task++){
      int kb=kb0+task*2;
      ushort8v hv, lv;
      #pragma unroll
      for(int j=0;j<8;j++){
        float x=pb[task][j];
        unsigned short h=f2bf(x);
        hv[j]=h;
        lv[j]=f2bf(x - bf2f(h));
      }
      *(ushort8v*)&Bh[nn][kb*8]=hv;
      *(ushort8v*)&Bl[nn][kb*8]=lv;
    }
    __syncthreads();
    // prefetch next K-step
    if(k0+32<K){
      #pragma unroll
      for(int q=0;q<4;q++) pa[q]=*(const float4v*)(Ag + k0+32 + q*4);
      #pragma unroll
      for(int j=0;j<8;j++){
        pb[0][j]=Wg[(size_t)(k0+32+kb0*8+j)*N];
        pb[1][j]=Wg[(size_t)(k0+32+(kb0+2)*8+j)*N];
      }
    }
    // compute
    int fr=lane&15;
    int koff=(lane>>4)*8;
    union { short8v s; bf16x8 b; } Bfh[4], Bfl[4];
    #pragma unroll
    for(int fj=0;fj<4;fj++){
      Bfh[fj].s = *(const short8v*)&Bh[wc+fj*16+fr][koff];
      Bfl[fj].s = *(const short8v*)&Bl[wc+fj*16+fr][koff];
    }
    #pragma unroll
    for(int fi=0;fi<4;fi++){
      union { short8v s; bf16x8 b; } Afh, Afl;
      Afh.s = *(const short8v*)&Ah[wr+fi*16+fr][koff];
      Afl.s = *(const short8v*)&Al[wr+fi*16+fr][koff];
      #pragma unroll
      for(int fj=0;fj<4;fj++){
        acc[fi][fj] = __builtin_amdgcn_mfma_f32_16x16x32_bf16(Afh.b, Bfh[fj].b, acc[fi][fj], 0,0,0);
        acc[fi][fj] = __builtin_amdgcn_mfma_f32_16x16x32_bf16(Afh.b, Bfl[fj].b, acc[fi][fj], 0,0,0);
        acc[fi][fj] = __builtin_amdgcn_mfma_f32_16x16x32_bf16(Afl.b, Bfh[fj].b, acc[fi][fj], 0,0,0);
      }
    }
  }

  // epilogue: D[row=(lane>>4)*4+reg][col=lane&15] per frag
  int fr=lane&15, r0=(lane>>4)*4;
  float bb4[4];
  #pragma unroll
  for(int fj=0;fj<4;fj++) bb4[fj]=bias[bn+wc+fj*16+fr];
  if(bn+128<=outC){
    #pragma unroll
    for(int fi=0;fi<4;fi++)
      #pragma unroll
      for(int fj=0;fj<4;fj++)
        #pragma unroll
        for(int rg=0;rg<4;rg++){
          size_t row=(size_t)(bm+wr+fi*16+r0+rg);
          Cc[row*outC + bn+wc+fj*16+fr]=acc[fi][fj][rg]+bb4[fj];
        }
  } else {
    int sw=7*outC, scol=bn-outC;
    #pragma unroll
    for(int fi=0;fi<4;fi++)
      #pragma unroll
      for(int fj=0;fj<4;fj++)
        #pragma unroll
        for(int rg=0;rg<4;rg++){
          size_t row=(size_t)(bm+wr+fi*16+r0+rg);
          Sp[row*sw + scol+wc+fj*16+fr]=f2bf(acc[fi][fj][rg]+bb4[fj]);
        }
  }
}

// ---------------- conv_layer aggregate (bf16 support gather) + BN-stats ----------------
// Round-3 version (best measured across 6 structural variants: ~68us @ C=128).
// Do not restructure (rounds 2/4/5/8 all regressed).
template<int C, int TPN, int NODES>
__global__ __launch_bounds__(TPN*NODES) void conv_agg_k(
    const float* __restrict__ cent, const unsigned short* __restrict__ sup,
    int Vb,
    const float* __restrict__ dirn, const int* __restrict__ nbidx,
    const float* __restrict__ cnd,
    float* __restrict__ outp, float* __restrict__ stats)
{
  constexpr int ncol = SUPN*C;
  constexpr int NT = TPN*NODES;
  int tid=threadIdx.x, nd=tid/TPN, t=tid%TPN;
  int b=blockIdx.y, i=blockIdx.x*NODES+nd;
  __shared__ float sd[NODES][32];
  __shared__ int snb[NODES][12];
  __shared__ float ssum[C], ssq[C];
  __shared__ float scn[3*ncol];
  if(t<30) sd[nd][t]=dirn[((size_t)(b*Vb+i))*30+t];
  if(t<10) snb[nd][t]=nbidx[(size_t)(b*Vb+i)*10+t];
  for(int c=tid;c<3*ncol;c+=NT) scn[c]=cnd[c];
  if(stats) for(int c=tid;c<C;c+=NT){ ssum[c]=0.0f; ssq[c]=0.0f; }
  __syncthreads();

  const int col0 = t*4;
  const unsigned short* fb = sup + (size_t)b*Vb*ncol;

  float m[SUPN][4];
  #pragma unroll
  for(int s=0;s<SUPN;s++)
    #pragma unroll
    for(int v=0;v<4;v++) m[s][v]=-INFINITY;

  ushort4v bufA[SUPN], bufB[SUPN];
  float dax,day,daz, dbx,dby,dbz;
  {
    unsigned int off=(unsigned int)snb[nd][0]*ncol + col0;
    #pragma unroll
    for(int s=0;s<SUPN;s++) bufA[s]=*(const ushort4v*)&fb[off + s*C];
    dax=sd[nd][0]; day=sd[nd][1]; daz=sd[nd][2];
  }
  #pragma unroll 1
  for(int np=0;np<5;np++){
    {
      int nn=2*np+1;
      unsigned int off=(unsigned int)snb[nd][nn]*ncol + col0;
      #pragma unroll
      for(int s=0;s<SUPN;s++) bufB[s]=*(const ushort4v*)&fb[off + s*C];
      dbx=sd[nd][3*nn]; dby=sd[nd][3*nn+1]; dbz=sd[nd][3*nn+2];
    }
    #pragma unroll
    for(int s=0;s<SUPN;s++){
      int cb=s*C+col0;
      float4v w0=*(const float4v*)&scn[cb];
      float4v w1=*(const float4v*)&scn[ncol+cb];
      float4v w2=*(const float4v*)&scn[2*ncol+cb];
      ushort4v sv=bufA[s];
      #pragma unroll
      for(int v=0;v<4;v++){
        float d = dax*w0[v] + day*w1[v] + daz*w2[v];
        m[s][v] = fmaxf(m[s][v], fast_silu(d)*bf2f(sv[v]));
      }
    }
    if(np<4){
      int nn=2*np+2;
      unsigned int off=(unsigned int)snb[nd][nn]*ncol + col0;
      #pragma unroll
      for(int s=0;s<SUPN;s++) bufA[s]=*(const ushort4v*)&fb[off + s*C];
      dax=sd[nd][3*nn]; day=sd[nd][3*nn+1]; daz=sd[nd][3*nn+2];
    }
    #pragma unroll
    for(int s=0;s<SUPN;s++){
      int cb=s*C+col0;
      float4v w0=*(const float4v*)&scn[cb];
      float4v w1=*(const float4v*)&scn[ncol+cb];
      float4v w2=*(const float4v*)&scn[2*ncol+cb];
      ushort4v sv=bufB[s];
      #pragma unroll
      for(int v=0;v<4;v++){
        float d = dbx*w0[v] + dby*w1[v] + dbz*w2[v];
        m[s][v] = fmaxf(m[s][v], fast_silu(d)*bf2f(sv[v]));
      }
    }
  }

  float acc[4];
  {
    float4v cv=*(const float4v*)&cent[(size_t)(b*Vb+i)*C + col0];
    #pragma unroll
    for(int v=0;v<4;v++){
      acc[v]=cv[v];
      #pragma unroll
      for(int s=0;s<SUPN;s++) acc[v]+=m[s][v];
    }
  }
  {
    float4v ov;
    #pragma unroll
    for(int v=0;v<4;v++) ov[v]=acc[v];
    *(float4v*)&outp[(size_t)(b*Vb+i)*C + col0]=ov;
  }
  if(stats){
    #pragma unroll
    for(int v=0;v<4;v++){
      atomicAdd(&ssum[col0+v], acc[v]);
      atomicAdd(&ssq[col0+v], acc[v]*acc[v]);
    }
    __syncthreads();
    for(int c=tid;c<C;c+=NT){
      atomicAdd(&stats[c], ssum[c]);
      atomicAdd(&stats[C+c], ssq[c]);
    }
  }
}

// ---------------- BN apply + silu, float4 (+ optional out-slice write) ----------------
__global__ void bn_silu_k(const float* __restrict__ xin, const float* __restrict__ sums,
                          float invM, int C, const float* __restrict__ g, const float* __restrict__ bb,
                          float* __restrict__ y, int nquad, float* __restrict__ osl, int cshift)
{
  int gid=blockIdx.x*blockDim.x+threadIdx.x;
  if(gid>=nquad) return;
  int base=gid*4;
  int c=base&(C-1);
  float4v xv=*(const float4v*)&xin[base];
  float4v sm=*(const float4v*)&sums[c];
  float4v sq=*(const float4v*)&sums[C+c];
  float4v gv=*(const float4v*)&g[c];
  float4v bv=*(const float4v*)&bb[c];
  float4v r;
  #pragma unroll
  for(int u=0;u<4;u++){
    float mean=sm[u]*invM;
    float var=sq[u]*invM - mean*mean;
    float v=(xv[u]-mean)*rsqrtf(var+1e-5f)*gv[u]+bv[u];
    r[u]=fast_silu(v);
  }
  *(float4v*)&y[base]=r;
  if(osl){
    int row=base>>cshift;
    *(float4v*)&osl[(size_t)row*1280 + c]=r;
  }
}

// ---------------- pool over first-4 of idx10 at perm rows + coord gather ----
template<int C, int NODES>
__global__ __launch_bounds__((C/4)*NODES) void pool_gather_k(
    const float* __restrict__ fm, int Vsrc,
    const int* __restrict__ idx10, const int* __restrict__ perm,
    const float* __restrict__ vsrc,
    float* __restrict__ fout, float* __restrict__ vout, int Vq)
{
  constexpr int TPN=C/4;
  int tid=threadIdx.x, nd=tid/TPN, t=tid%TPN;
  int b=blockIdx.y, j=blockIdx.x*NODES+nd;
  int r=perm[j];
  const int* id=idx10+((size_t)b*Vsrc+r)*10;
  const float* fb=fm+(size_t)b*Vsrc*C;
  float4v m=(float4v)(-INFINITY);
  #pragma unroll
  for(int n=0;n<4;n++){
    float4v fv=*(const float4v*)&fb[(size_t)id[n]*C + t*4];
    #pragma unroll
    for(int u=0;u<4;u++) m[u]=fmaxf(m[u],fv[u]);
  }
  *(float4v*)&fout[(size_t)(b*Vq+j)*C + t*4]=m;
  if(t<3) vout[((size_t)b*Vq+j)*3+t]=vsrc[((size_t)b*Vsrc+r)*3+t];
}

// ---------------- fused nearest (v1,v2) + upsample concat ----------------
__global__ __launch_bounds__(512) void nearest_concat_k(
    const float* __restrict__ v1, const float* __restrict__ v2,
    const float* __restrict__ x,
    const float* __restrict__ fm2, const float* __restrict__ fm3,
    const float* __restrict__ fm4,
    float* __restrict__ outp)
{
  __shared__ float4v s1[V1N];
  __shared__ float4v s2[V2N];
  int t=threadIdx.x;
  int lane=t&63, wv=t>>6;
  int b=blockIdx.y; int j=blockIdx.x*8+wv;
  const float* c1=v1+(size_t)b*V1N*3;
  const float* c2=v2+(size_t)b*V2N*3;
  for(int i=t;i<V1N;i+=512){
    float xx=c1[3*i],yy=c1[3*i+1],zz=c1[3*i+2];
    float4v v; v[0]=xx;v[1]=yy;v[2]=zz;v[3]=xx*xx+yy*yy+zz*zz; s1[i]=v;
  }
  for(int i=t;i<V2N;i+=512){
    float xx=c2[3*i],yy=c2[3*i+1],zz=c2[3*i+2];
    float4v v; v[0]=xx;v[1]=yy;v[2]=zz;v[3]=xx*xx+yy*yy+zz*zz; s2[i]=v;
  }
  __syncthreads();
  const float* qb=x+(size_t)b*V0*3;
  float qx=qb[3*j],qy=qb[3*j+1],qz=qb[3*j+2];
  float qs=qx*qx+qy*qy+qz*qz;
  u64 bk=~0ull;
  #pragma unroll 4
  for(int c=0;c<V1N/64;c++){
    int i=c*64+lane;
    float4v p=s1[i];
    float dot=qx*p[0]+qy*p[1]+qz*p[2];
    float d=fmaf(-2.0f,dot,p[3]+qs);
    u64 k=((u64)fkey(d)<<32)|(unsigned int)i;
    bk = k<bk ? k : bk;
  }
  #pragma unroll
  for(int s=32;s;s>>=1){ u64 o=shfl_xor_u64(bk,s); bk = o<bk?o:bk; }
  int j1=(int)(bk&0xffffffffu);
  bk=~0ull;
  #pragma unroll 4
  for(int c=0;c<V2N/64;c++){
    int i=c*64+lane;
    float4v p=s2[i];
    float dot=qx*p[0]+qy*p[1]+qz*p[2];
    float d=fmaf(-2.0f,dot,p[3]+qs);
    u64 k=((u64)fkey(d)<<32)|(unsigned int)i;
    bk = k<bk ? k : bk;
  }
  #pragma unroll
  for(int s=32;s;s>>=1){ u64 o=shfl_xor_u64(bk,s); bk = o<bk?o:bk; }
  int j2=(int)(bk&0xffffffffu);

  const float4v* f2p=(const float4v*)(fm2 + ((size_t)b*V1N+j1)*256);
  const float4v* f3p=(const float4v*)(fm3 + ((size_t)b*V1N+j1)*256);
  const float4v* f4p=(const float4v*)(fm4 + ((size_t)b*V2N+j2)*512);
  float4v* op=(float4v*)(outp + (size_t)(b*V0+j)*1280) + 64;
  op[lane]       = f2p[lane];
  op[64+lane]    = f3p[lane];
  op[128+lane]   = f4p[lane];
  op[192+lane]   = f4p[64+lane];
}

extern "C" void kernel_launch(void* const* d_in, const int* in_sizes, int n_in,
                              void* d_out, int out_size, void* d_ws, size_t ws_size,
                              hipStream_t stream) {
  const float* x   =(const float*)d_in[0];
  const float* d0  =(const float*)d_in[1];
  const float* w1  =(const float*)d_in[2];
  const float* b1  =(const float*)d_in[3];
  const float* dir1=(const float*)d_in[4];
  const float* g1  =(const float*)d_in[5];
  const float* bb1 =(const float*)d_in[6];
  const float* w2  =(const float*)d_in[7];
  const float* b2  =(const float*)d_in[8];
  const float* dir2=(const float*)d_in[9];
  const float* g2  =(const float*)d_in[10];
  const float* bb2 =(const float*)d_in[11];
  const float* w3  =(const float*)d_in[12];
  const float* b3  =(const float*)d_in[13];
  const float* dir3=(const float*)d_in[14];
  const float* g3  =(const float*)d_in[15];
  const float* bb3 =(const float*)d_in[16];
  const float* w4  =(const float*)d_in[17];
  const float* b4  =(const float*)d_in[18];
  const float* dir4=(const float*)d_in[19];
  const int* perm1 =(const int*)d_in[20];
  const int* perm2 =(const int*)d_in[21];
  float* out=(float*)d_out;

  float* w=(float*)d_ws;
  size_t off=0;
  auto alloc=[&](size_t n){ float* p=w+off; off+=n; return p; };
  float* cn0 =alloc(2688);
  float* cn1 =alloc(2688);
  float* cn2 =alloc(5376);
  float* cn3 =alloc(5376);
  float* cn4 =alloc(10752);
  float* dirnx =alloc((size_t)BNUM*V0*30);
  float* dirnv1=alloc((size_t)BNUM*V1N*30);
  float* dirnv2=alloc((size_t)BNUM*V2N*30);
  float* fm0 =alloc((size_t)BNUM*V0*128);
  float* cent=alloc((size_t)BNUM*V0*128);
  unsigned short* supb=(unsigned short*)alloc((size_t)BNUM*V0*896/2);
  float* fm1r=alloc((size_t)BNUM*V0*128);
  float* fm1 =alloc((size_t)BNUM*V0*128);
  float* f1  =alloc((size_t)BNUM*V1N*128);
  float* v1  =alloc((size_t)BNUM*V1N*3);
  float* fm2r=alloc((size_t)BNUM*V1N*256);
  float* fm2 =alloc((size_t)BNUM*V1N*256);
  float* fm3r=alloc((size_t)BNUM*V1N*256);
  float* fm3 =alloc((size_t)BNUM*V1N*256);
  float* f2  =alloc((size_t)BNUM*V2N*256);
  float* v2  =alloc((size_t)BNUM*V2N*3);
  float* fm4 =alloc((size_t)BNUM*V2N*512);
  float* stats=alloc(1280);
  int* idx10x =(int*)alloc((size_t)BNUM*V0*10);
  int* idx10v1=(int*)alloc((size_t)BNUM*V1N*10);
  int* idx10v2=(int*)alloc((size_t)BNUM*V2N*10);

  colnorm_all_k<<<dim3(35),256,0,stream>>>(d0,dir1,dir2,dir3,dir4,cn0,cn1,cn2,cn3,cn4,stats);

  // knn10 on x
  knn10_k<V0,1024,4><<<dim3(V0/16,BNUM),1024,0,stream>>>(x, idx10x, dirnx);
  // fm0 = silu(conv_surface) -> fm0 scratch + out[:, :128]
  conv_surf_k<4><<<dim3(V0/4,BNUM),256,0,stream>>>(dirnx, cn0, fm0, out);

  // layer 1 (C=128): GEMM 8192x1024x128
  gemm_mfma_k<<<dim3(1024/128,(BNUM*V0)/128),256,0,stream>>>(fm0, w1, b1, cent, supb, BNUM*V0, 1024, 128, 128);
  conv_agg_k<128,32,8><<<dim3(V0/8,BNUM),256,0,stream>>>(cent, supb, V0, dirnx, idx10x, cn1, fm1r, stats);
  bn_silu_k<<<dim3((BNUM*V0*128/4)/256),256,0,stream>>>(fm1r, stats, 1.0f/(BNUM*V0), 128, g1, bb1, fm1, BNUM*V0*128/4, out+128, 7);

  // pool (first-4 of idx10x at perm1) + v1 gather
  pool_gather_k<128,8><<<dim3(V1N/8,BNUM),256,0,stream>>>(fm1, V0, idx10x, perm1, x, f1, v1, V1N);

  // knn10 on v1
  knn10_k<V1N,256,6><<<dim3(V1N/4,BNUM),256,0,stream>>>(v1, idx10v1, dirnv1);

  // layer 2 (C=256): GEMM 2048x2048x128
  gemm_mfma_k<<<dim3(2048/128,(BNUM*V1N)/128),256,0,stream>>>(f1, w2, b2, cent, supb, BNUM*V1N, 2048, 128, 256);
  conv_agg_k<256,64,4><<<dim3(V1N/4,BNUM),256,0,stream>>>(cent, supb, V1N, dirnv1, idx10v1, cn2, fm2r, stats+256);
  bn_silu_k<<<dim3((BNUM*V1N*256/4)/256),256,0,stream>>>(fm2r, stats+256, 1.0f/(BNUM*V1N), 256, g2, bb2, fm2, BNUM*V1N*256/4, nullptr, 8);

  // layer 3 (C=256): GEMM 2048x2048x256
  gemm_mfma_k<<<dim3(2048/128,(BNUM*V1N)/128),256,0,stream>>>(fm2, w3, b3, cent, supb, BNUM*V1N, 2048, 256, 256);
  conv_agg_k<256,64,4><<<dim3(V1N/4,BNUM),256,0,stream>>>(cent, supb, V1N, dirnv1, idx10v1, cn3, fm3r, stats+768);
  bn_silu_k<<<dim3((BNUM*V1N*256/4)/256),256,0,stream>>>(fm3r, stats+768, 1.0f/(BNUM*V1N), 256, g3, bb3, fm3, BNUM*V1N*256/4, nullptr, 8);

  // pool (first-4 of idx10v1 at perm2) + v2 gather
  pool_gather_k<256,4><<<dim3(V2N/4,BNUM),256,0,stream>>>(fm3, V1N, idx10v1, perm2, v1, f2, v2, V2N);

  // knn10 on v2
  knn10_k<V2N,256,6><<<dim3(V2N/4,BNUM),256,0,stream>>>(v2, idx10v2, dirnv2);

  // layer 4 (C=512): GEMM 512x4096x256, no bn/silu
  gemm_mfma_k<<<dim3(4096/128,(BNUM*V2N)/128),256,0,stream>>>(f2, w4, b4, cent, supb, BNUM*V2N, 4096, 256, 512);
  conv_agg_k<512,128,2><<<dim3(V2N/2,BNUM),256,0,stream>>>(cent, supb, V2N, dirnv2, idx10v2, cn4, fm4, nullptr);

  // fused nearest + upsample concat
  nearest_concat_k<<<dim3(V0/8,BNUM),512,0,stream>>>(v1, v2, x, fm2, fm3, fm4, out);
}

// Round 15
// 423.882 us; speedup vs baseline: 1.0856x; 1.0728x over previous
//
#include <hip/hip_runtime.h>
#include <math.h>
#include <float.h>
#include <limits.h>

#define BNUM 2
#define V0 4096
#define V1N 1024
#define V2N 256
#define SUPN 7

typedef float float4v __attribute__((ext_vector_type(4)));
typedef float float2v __attribute__((ext_vector_type(2)));
typedef unsigned short ushort4v __attribute__((ext_vector_type(4)));
typedef unsigned short ushort8v __attribute__((ext_vector_type(8)));
typedef short short8v __attribute__((ext_vector_type(8)));
typedef __bf16 bf16x8 __attribute__((ext_vector_type(8)));
typedef unsigned long long u64;

__device__ __forceinline__ float fast_silu(float x){
  return __fdividef(x, 1.0f + __expf(-x));
}

// RNE float -> bf16
__device__ __forceinline__ unsigned short f2bf(float f){
  unsigned int u=__float_as_uint(f);
  u += 0x7FFFu + ((u>>16)&1u);
  return (unsigned short)(u>>16);
}
__device__ __forceinline__ float bf2f(unsigned short h){
  return __uint_as_float(((unsigned int)h)<<16);
}

// exact monotone float->uint transform
__device__ __forceinline__ unsigned int fkey(float f){
  unsigned int u = __float_as_uint(f);
  int m = ((int)u) >> 31;
  return u ^ (unsigned int)(m | 0x80000000);
}

__device__ __forceinline__ u64 shfl_xor_u64(u64 v, int m){
  unsigned int lo = (unsigned int)v, hi = (unsigned int)(v>>32);
  lo = (unsigned int)__shfl_xor((int)lo, m);
  hi = (unsigned int)__shfl_xor((int)hi, m);
  return ((u64)hi<<32) | lo;
}

// ---------------- fused column-normalize + stats zero ----------------
__global__ void colnorm_all_k(const float* __restrict__ d0, const float* __restrict__ dir1,
                              const float* __restrict__ dir2, const float* __restrict__ dir3,
                              const float* __restrict__ dir4,
                              float* __restrict__ cn0, float* __restrict__ cn1,
                              float* __restrict__ cn2, float* __restrict__ cn3,
                              float* __restrict__ cn4, float* __restrict__ stats){
  int c = blockIdx.x*256 + threadIdx.x;
  if(c < 1280) stats[c] = 0.0f;
  const float* s; float* o; int nc;
  if(c < 896){ s=d0; o=cn0; nc=896; }
  else if((c-=896) < 896){ s=dir1; o=cn1; nc=896; }
  else if((c-=896) < 1792){ s=dir2; o=cn2; nc=1792; }
  else if((c-=1792) < 1792){ s=dir3; o=cn3; nc=1792; }
  else { c-=1792; if(c>=3584) return; s=dir4; o=cn4; nc=3584; }
  float a=s[c], b=s[nc+c], e=s[2*nc+c];
  float n=sqrtf(a*a+b*b+e*e); n=fmaxf(n,1e-12f);
  o[c]=a/n; o[nc+c]=b/n; o[2*nc+c]=e/n;
}

// ---------------- self-KNN (k=10, skip self) ----------------
template<int VC, int THREADS, int MINW>
__global__ __launch_bounds__(THREADS, MINW) void knn10_k(const float* __restrict__ pts,
    int* __restrict__ out_idx, float* __restrict__ out_dirn)
{
  constexpr int CHUNK = VC/64;
  constexpr int QPB = THREADS/64;
  __shared__ float4v sp4[VC];
  __shared__ float sdd[QPB][34];
  __shared__ int   sdi[QPB][34];
  int t = threadIdx.x;
  int lane = t & 63;
  int wv   = t >> 6;
  int b = blockIdx.y;
  int j = blockIdx.x*QPB + wv;
  const float* pb = pts + (size_t)b*VC*3;
  for(int i=t; i<VC; i+=THREADS){
    float x=pb[3*i], y=pb[3*i+1], z=pb[3*i+2];
    float4v v; v[0]=x; v[1]=y; v[2]=z; v[3]=x*x+y*y+z*z;
    sp4[i]=v;
  }
  __syncthreads();
  float qx=pb[3*j], qy=pb[3*j+1], qz=pb[3*j+2];
  float qs=qx*qx+qy*qy+qz*qz;

  float dc[CHUNK];
  float p0=INFINITY, p1=INFINITY, p2=INFINITY, p3=INFINITY;
  #pragma unroll
  for(int c=0;c<CHUNK;c++){
    float4v p = sp4[c*64+lane];
    float dot = qx*p[0]+qy*p[1]+qz*p[2];
    float d = fmaf(-2.0f, dot, p[3]+qs);
    dc[c]=d;
    float s=d, a;
    a=fminf(p0,s); s=fmaxf(p0,s); p0=a;
    a=fminf(p1,s); s=fmaxf(p1,s); p1=a;
    a=fminf(p2,s); s=fmaxf(p2,s); p2=a;
    p3=fminf(p3,s);
  }

  float prev=-INFINITY;
  for(int sel=0; sel<11; ++sel){
    float cand = p0>prev ? p0 : (p1>prev ? p1 : (p2>prev ? p2 : (p3>prev ? p3 : INFINITY)));
    #pragma unroll
    for(int s=32;s;s>>=1) cand = fminf(cand, __shfl_xor(cand, s));
    prev=cand;
  }
  float v11 = prev;

  int cnt=0;
  #pragma unroll
  for(int c=0;c<CHUNK;c++){
    bool hit = dc[c] <= v11;
    u64 m = __ballot(hit);
    if(m){
      if(hit){
        int pos = cnt + __popcll(m & ((1ull<<lane)-1ull));
        if(pos<32){ sdd[wv][pos]=dc[c]; sdi[wv][pos]=c*64+lane; }
      }
      cnt += (int)__popcll(m);
    }
  }
  if(cnt>32) cnt=32;

  if(lane < cnt){
    float dl = sdd[wv][lane]; int il = sdi[wv][lane];
    int rank=0;
    for(int m2=0;m2<cnt;m2++){
      float dm=sdd[wv][m2]; int im=sdi[wv][m2];
      rank += (dm<dl || (dm==dl && im<il)) ? 1 : 0;
    }
    if(rank>=1 && rank<=10){
      size_t obase=((size_t)b*VC+j)*10 + (rank-1);
      out_idx[obase]=il;
      float4v p = sp4[il];
      float dx=p[0]-qx, dy=p[1]-qy, dz=p[2]-qz;
      float n=sqrtf(dx*dx+dy*dy+dz*dz); n=fmaxf(n,1e-12f);
      out_dirn[obase*3]=dx/n; out_dirn[obase*3+1]=dy/n; out_dirn[obase*3+2]=dz/n;
    }
  }
}

// ---------------- conv_surface + outer silu -> fm0 + out[:, :128] ----------------
template<int NODES>
__global__ __launch_bounds__(64*NODES) void conv_surf_k(
    const float* __restrict__ dirn, const float* __restrict__ cnd,
    float* __restrict__ fm0, float* __restrict__ outbuf)
{
  int tid=threadIdx.x, nd=tid>>6, t=tid&63;
  int b=blockIdx.y, i=blockIdx.x*NODES+nd;
  __shared__ float sd[NODES][32];
  if(t<30) sd[nd][t]=dirn[((size_t)(b*V0+i))*30+t];
  __syncthreads();
  float acc0=0.0f, acc1=0.0f;
  for(int s=0;s<SUPN;s++){
    int col=s*128+t;
    float wa0=cnd[col],     wa1=cnd[896+col],     wa2=cnd[1792+col];
    float wb0=cnd[col+64],  wb1=cnd[896+col+64],  wb2=cnd[1792+col+64];
    float m0=-INFINITY, m1=-INFINITY;
    #pragma unroll
    for(int n=0;n<10;n++){
      float dx=sd[nd][3*n], dy=sd[nd][3*n+1], dz=sd[nd][3*n+2];
      m0=fmaxf(m0, fast_silu(dx*wa0+dy*wa1+dz*wa2));
      m1=fmaxf(m1, fast_silu(dx*wb0+dy*wb1+dz*wb2));
    }
    acc0+=m0; acc1+=m1;
  }
  float r0=fast_silu(acc0), r1=fast_silu(acc1);
  size_t frow=(size_t)(b*V0+i)*128;
  fm0[frow+t]=r0; fm0[frow+64+t]=r1;
  size_t orow=(size_t)(b*V0+i)*1280;
  outbuf[orow+t]=r0; outbuf[orow+64+t]=r1;
}

// ---------------- MFMA GEMM, bf16x2-split (hi/lo), split epilogue ----------------
// x = hi + lo (both bf16); D = Ah*Bh + Ah*Bl + Al*Bh accumulated in fp32 MFMA.
// LDS rows: 40 ushorts (80B = 20 dwords). Bank math: fr*20 mod 32 has period 8
// -> fragment reads 2-way (free, m136), staging writes ~4-way. LDS total
// 4*128*40*2 = 40KB -> 4 blocks/CU (48-row: 3 blocks + 4-way reads;
// 56-row: 2 blocks — both measured worse; rounds 12/13).
__global__ __launch_bounds__(256) void gemm_mfma_k(
    const float* __restrict__ A, const float* __restrict__ W,
    const float* __restrict__ bias,
    float* __restrict__ Cc, unsigned short* __restrict__ Sp,
    int M, int N, int K, int outC)
{
  __shared__ __attribute__((aligned(16))) unsigned short Ah[128][40];
  __shared__ __attribute__((aligned(16))) unsigned short Al[128][40];
  __shared__ __attribute__((aligned(16))) unsigned short Bh[128][40];
  __shared__ __attribute__((aligned(16))) unsigned short Bl[128][40];
  int t=threadIdx.x;
  int lane=t&63, wv=t>>6;
  int wr=(wv>>1)*64, wc=(wv&1)*64;
  int bm=blockIdx.y*128, bn=blockIdx.x*128;

  float4v acc[4][4];
  #pragma unroll
  for(int fi=0;fi<4;fi++)
    #pragma unroll
    for(int fj=0;fj<4;fj++) acc[fi][fj]=(float4v)(0.0f);

  // A staging: thread covers row ar, k-quads (af..af+3) => k in [af*4, af*4+16)
  int ar=t>>1, af=(t&1)*4;
  const float* Ag = A + (size_t)(bm+ar)*K + af*4;
  // B staging: two tasks, col nn, k-blocks kb0 and kb0+2 (8 k's each)
  int nn=t&127, kb0=t>>7;
  const float* Wg = W + bn + nn;

  float4v pa[4];
  float pb[2][8];
  #pragma unroll
  for(int q=0;q<4;q++) pa[q]=*(const float4v*)(Ag + q*4);
  #pragma unroll
  for(int j=0;j<8;j++){
    pb[0][j]=Wg[(size_t)(kb0*8+j)*N];
    pb[1][j]=Wg[(size_t)((kb0+2)*8+j)*N];
  }

  for(int k0=0;k0<K;k0+=32){
    __syncthreads();
    // convert + stage
    #pragma unroll
    for(int q=0;q<4;q++){
      ushort4v hv, lv;
      #pragma unroll
      for(int i2=0;i2<4;i2++){
        float x=pa[q][i2];
        unsigned short h=f2bf(x);
        hv[i2]=h;
        lv[i2]=f2bf(x - bf2f(h));
      }
      *(ushort4v*)&Ah[ar][(af+q)*4]=hv;
      *(ushort4v*)&Al[ar][(af+q)*4]=lv;
    }
    #pragma unroll
    for(int task=0;task<2;task++){
      int kb=kb0+task*2;
      ushort8v hv, lv;
      #pragma unroll
      for(int j=0;j<8;j++){
        float x=pb[task][j];
        unsigned short h=f2bf(x);
        hv[j]=h;
        lv[j]=f2bf(x - bf2f(h));
      }
      *(ushort8v*)&Bh[nn][kb*8]=hv;
      *(ushort8v*)&Bl[nn][kb*8]=lv;
    }
    __syncthreads();
    // prefetch next K-step
    if(k0+32<K){
      #pragma unroll
      for(int q=0;q<4;q++) pa[q]=*(const float4v*)(Ag + k0+32 + q*4);
      #pragma unroll
      for(int j=0;j<8;j++){
        pb[0][j]=Wg[(size_t)(k0+32+kb0*8+j)*N];
        pb[1][j]=Wg[(size_t)(k0+32+(kb0+2)*8+j)*N];
      }
    }
    // compute
    int fr=lane&15;
    int koff=(lane>>4)*8;
    union { short8v s; bf16x8 b; } Bfh[4], Bfl[4];
    #pragma unroll
    for(int fj=0;fj<4;fj++){
      Bfh[fj].s = *(const short8v*)&Bh[wc+fj*16+fr][koff];
      Bfl[fj].s = *(const short8v*)&Bl[wc+fj*16+fr][koff];
    }
    #pragma unroll
    for(int fi=0;fi<4;fi++){
      union { short8v s; bf16x8 b; } Afh, Afl;
      Afh.s = *(const short8v*)&Ah[wr+fi*16+fr][koff];
      Afl.s = *(const short8v*)&Al[wr+fi*16+fr][koff];
      #pragma unroll
      for(int fj=0;fj<4;fj++){
        acc[fi][fj] = __builtin_amdgcn_mfma_f32_16x16x32_bf16(Afh.b, Bfh[fj].b, acc[fi][fj], 0,0,0);
        acc[fi][fj] = __builtin_amdgcn_mfma_f32_16x16x32_bf16(Afh.b, Bfl[fj].b, acc[fi][fj], 0,0,0);
        acc[fi][fj] = __builtin_amdgcn_mfma_f32_16x16x32_bf16(Afl.b, Bfh[fj].b, acc[fi][fj], 0,0,0);
      }
    }
  }

  // epilogue: D[row=(lane>>4)*4+reg][col=lane&15] per frag
  int fr=lane&15, r0=(lane>>4)*4;
  float bb4[4];
  #pragma unroll
  for(int fj=0;fj<4;fj++) bb4[fj]=bias[bn+wc+fj*16+fr];
  if(bn+128<=outC){
    #pragma unroll
    for(int fi=0;fi<4;fi++)
      #pragma unroll
      for(int fj=0;fj<4;fj++)
        #pragma unroll
        for(int rg=0;rg<4;rg++){
          size_t row=(size_t)(bm+wr+fi*16+r0+rg);
          Cc[row*outC + bn+wc+fj*16+fr]=acc[fi][fj][rg]+bb4[fj];
        }
  } else {
    int sw=7*outC, scol=bn-outC;
    #pragma unroll
    for(int fi=0;fi<4;fi++)
      #pragma unroll
      for(int fj=0;fj<4;fj++)
        #pragma unroll
        for(int rg=0;rg<4;rg++){
          size_t row=(size_t)(bm+wr+fi*16+r0+rg);
          Sp[row*sw + scol+wc+fj*16+fr]=f2bf(acc[fi][fj][rg]+bb4[fj]);
        }
  }
}

// ---------------- conv_layer aggregate (bf16 support gather) + BN-stats ----------------
// Round-3 version (best measured across 6 structural variants: ~68us @ C=128).
// Do not restructure (rounds 2/4/5/8 all regressed).
template<int C, int TPN, int NODES>
__global__ __launch_bounds__(TPN*NODES) void conv_agg_k(
    const float* __restrict__ cent, const unsigned short* __restrict__ sup,
    int Vb,
    const float* __restrict__ dirn, const int* __restrict__ nbidx,
    const float* __restrict__ cnd,
    float* __restrict__ outp, float* __restrict__ stats)
{
  constexpr int ncol = SUPN*C;
  constexpr int NT = TPN*NODES;
  int tid=threadIdx.x, nd=tid/TPN, t=tid%TPN;
  int b=blockIdx.y, i=blockIdx.x*NODES+nd;
  __shared__ float sd[NODES][32];
  __shared__ int snb[NODES][12];
  __shared__ float ssum[C], ssq[C];
  __shared__ float scn[3*ncol];
  if(t<30) sd[nd][t]=dirn[((size_t)(b*Vb+i))*30+t];
  if(t<10) snb[nd][t]=nbidx[(size_t)(b*Vb+i)*10+t];
  for(int c=tid;c<3*ncol;c+=NT) scn[c]=cnd[c];
  if(stats) for(int c=tid;c<C;c+=NT){ ssum[c]=0.0f; ssq[c]=0.0f; }
  __syncthreads();

  const int col0 = t*4;
  const unsigned short* fb = sup + (size_t)b*Vb*ncol;

  float m[SUPN][4];
  #pragma unroll
  for(int s=0;s<SUPN;s++)
    #pragma unroll
    for(int v=0;v<4;v++) m[s][v]=-INFINITY;

  ushort4v bufA[SUPN], bufB[SUPN];
  float dax,day,daz, dbx,dby,dbz;
  {
    unsigned int off=(unsigned int)snb[nd][0]*ncol + col0;
    #pragma unroll
    for(int s=0;s<SUPN;s++) bufA[s]=*(const ushort4v*)&fb[off + s*C];
    dax=sd[nd][0]; day=sd[nd][1]; daz=sd[nd][2];
  }
  #pragma unroll 1
  for(int np=0;np<5;np++){
    {
      int nn=2*np+1;
      unsigned int off=(unsigned int)snb[nd][nn]*ncol + col0;
      #pragma unroll
      for(int s=0;s<SUPN;s++) bufB[s]=*(const ushort4v*)&fb[off + s*C];
      dbx=sd[nd][3*nn]; dby=sd[nd][3*nn+1]; dbz=sd[nd][3*nn+2];
    }
    #pragma unroll
    for(int s=0;s<SUPN;s++){
      int cb=s*C+col0;
      float4v w0=*(const float4v*)&scn[cb];
      float4v w1=*(const float4v*)&scn[ncol+cb];
      float4v w2=*(const float4v*)&scn[2*ncol+cb];
      ushort4v sv=bufA[s];
      #pragma unroll
      for(int v=0;v<4;v++){
        float d = dax*w0[v] + day*w1[v] + daz*w2[v];
        m[s][v] = fmaxf(m[s][v], fast_silu(d)*bf2f(sv[v]));
      }
    }
    if(np<4){
      int nn=2*np+2;
      unsigned int off=(unsigned int)snb[nd][nn]*ncol + col0;
      #pragma unroll
      for(int s=0;s<SUPN;s++) bufA[s]=*(const ushort4v*)&fb[off + s*C];
      dax=sd[nd][3*nn]; day=sd[nd][3*nn+1]; daz=sd[nd][3*nn+2];
    }
    #pragma unroll
    for(int s=0;s<SUPN;s++){
      int cb=s*C+col0;
      float4v w0=*(const float4v*)&scn[cb];
      float4v w1=*(const float4v*)&scn[ncol+cb];
      float4v w2=*(const float4v*)&scn[2*ncol+cb];
      ushort4v sv=bufB[s];
      #pragma unroll
      for(int v=0;v<4;v++){
        float d = dbx*w0[v] + dby*w1[v] + dbz*w2[v];
        m[s][v] = fmaxf(m[s][v], fast_silu(d)*bf2f(sv[v]));
      }
    }
  }

  float acc[4];
  {
    float4v cv=*(const float4v*)&cent[(size_t)(b*Vb+i)*C + col0];
    #pragma unroll
    for(int v=0;v<4;v++){
      acc[v]=cv[v];
      #pragma unroll
      for(int s=0;s<SUPN;s++) acc[v]+=m[s][v];
    }
  }
  {
    float4v ov;
    #pragma unroll
    for(int v=0;v<4;v++) ov[v]=acc[v];
    *(float4v*)&outp[(size_t)(b*Vb+i)*C + col0]=ov;
  }
  if(stats){
    #pragma unroll
    for(int v=0;v<4;v++){
      atomicAdd(&ssum[col0+v], acc[v]);
      atomicAdd(&ssq[col0+v], acc[v]*acc[v]);
    }
    __syncthreads();
    for(int c=tid;c<C;c+=NT){
      atomicAdd(&stats[c], ssum[c]);
      atomicAdd(&stats[C+c], ssq[c]);
    }
  }
}

// ---------------- BN apply + silu, float4 (+ optional out-slice write) ----------------
__global__ void bn_silu_k(const float* __restrict__ xin, const float* __restrict__ sums,
                          float invM, int C, const float* __restrict__ g, const float* __restrict__ bb,
                          float* __restrict__ y, int nquad, float* __restrict__ osl, int cshift)
{
  int gid=blockIdx.x*blockDim.x+threadIdx.x;
  if(gid>=nquad) return;
  int base=gid*4;
  int c=base&(C-1);
  float4v xv=*(const float4v*)&xin[base];
  float4v sm=*(const float4v*)&sums[c];
  float4v sq=*(const float4v*)&sums[C+c];
  float4v gv=*(const float4v*)&g[c];
  float4v bv=*(const float4v*)&bb[c];
  float4v r;
  #pragma unroll
  for(int u=0;u<4;u++){
    float mean=sm[u]*invM;
    float var=sq[u]*invM - mean*mean;
    float v=(xv[u]-mean)*rsqrtf(var+1e-5f)*gv[u]+bv[u];
    r[u]=fast_silu(v);
  }
  *(float4v*)&y[base]=r;
  if(osl){
    int row=base>>cshift;
    *(float4v*)&osl[(size_t)row*1280 + c]=r;
  }
}

// ---------------- pool over first-4 of idx10 at perm rows + coord gather ----
template<int C, int NODES>
__global__ __launch_bounds__((C/4)*NODES) void pool_gather_k(
    const float* __restrict__ fm, int Vsrc,
    const int* __restrict__ idx10, const int* __restrict__ perm,
    const float* __restrict__ vsrc,
    float* __restrict__ fout, float* __restrict__ vout, int Vq)
{
  constexpr int TPN=C/4;
  int tid=threadIdx.x, nd=tid/TPN, t=tid%TPN;
  int b=blockIdx.y, j=blockIdx.x*NODES+nd;
  int r=perm[j];
  const int* id=idx10+((size_t)b*Vsrc+r)*10;
  const float* fb=fm+(size_t)b*Vsrc*C;
  float4v m=(float4v)(-INFINITY);
  #pragma unroll
  for(int n=0;n<4;n++){
    float4v fv=*(const float4v*)&fb[(size_t)id[n]*C + t*4];
    #pragma unroll
    for(int u=0;u<4;u++) m[u]=fmaxf(m[u],fv[u]);
  }
  *(float4v*)&fout[(size_t)(b*Vq+j)*C + t*4]=m;
  if(t<3) vout[((size_t)b*Vq+j)*3+t]=vsrc[((size_t)b*Vsrc+r)*3+t];
}

// ---------------- fused nearest (v1,v2) + upsample concat ----------------
__global__ __launch_bounds__(512) void nearest_concat_k(
    const float* __restrict__ v1, const float* __restrict__ v2,
    const float* __restrict__ x,
    const float* __restrict__ fm2, const float* __restrict__ fm3,
    const float* __restrict__ fm4,
    float* __restrict__ outp)
{
  __shared__ float4v s1[V1N];
  __shared__ float4v s2[V2N];
  int t=threadIdx.x;
  int lane=t&63, wv=t>>6;
  int b=blockIdx.y; int j=blockIdx.x*8+wv;
  const float* c1=v1+(size_t)b*V1N*3;
  const float* c2=v2+(size_t)b*V2N*3;
  for(int i=t;i<V1N;i+=512){
    float xx=c1[3*i],yy=c1[3*i+1],zz=c1[3*i+2];
    float4v v; v[0]=xx;v[1]=yy;v[2]=zz;v[3]=xx*xx+yy*yy+zz*zz; s1[i]=v;
  }
  for(int i=t;i<V2N;i+=512){
    float xx=c2[3*i],yy=c2[3*i+1],zz=c2[3*i+2];
    float4v v; v[0]=xx;v[1]=yy;v[2]=zz;v[3]=xx*xx+yy*yy+zz*zz; s2[i]=v;
  }
  __syncthreads();
  const float* qb=x+(size_t)b*V0*3;
  float qx=qb[3*j],qy=qb[3*j+1],qz=qb[3*j+2];
  float qs=qx*qx+qy*qy+qz*qz;
  u64 bk=~0ull;
  #pragma unroll 4
  for(int c=0;c<V1N/64;c++){
    int i=c*64+lane;
    float4v p=s1[i];
    float dot=qx*p[0]+qy*p[1]+qz*p[2];
    float d=fmaf(-2.0f,dot,p[3]+qs);
    u64 k=((u64)fkey(d)<<32)|(unsigned int)i;
    bk = k<bk ? k : bk;
  }
  #pragma unroll
  for(int s=32;s;s>>=1){ u64 o=shfl_xor_u64(bk,s); bk = o<bk?o:bk; }
  int j1=(int)(bk&0xffffffffu);
  bk=~0ull;
  #pragma unroll 4
  for(int c=0;c<V2N/64;c++){
    int i=c*64+lane;
    float4v p=s2[i];
    float dot=qx*p[0]+qy*p[1]+qz*p[2];
    float d=fmaf(-2.0f,dot,p[3]+qs);
    u64 k=((u64)fkey(d)<<32)|(unsigned int)i;
    bk = k<bk ? k : bk;
  }
  #pragma unroll
  for(int s=32;s;s>>=1){ u64 o=shfl_xor_u64(bk,s); bk = o<bk?o:bk; }
  int j2=(int)(bk&0xffffffffu);

  const float4v* f2p=(const float4v*)(fm2 + ((size_t)b*V1N+j1)*256);
  const float4v* f3p=(const float4v*)(fm3 + ((size_t)b*V1N+j1)*256);
  const float4v* f4p=(const float4v*)(fm4 + ((size_t)b*V2N+j2)*512);
  float4v* op=(float4v*)(outp + (size_t)(b*V0+j)*1280) + 64;
  op[lane]       = f2p[lane];
  op[64+lane]    = f3p[lane];
  op[128+lane]   = f4p[lane];
  op[192+lane]   = f4p[64+lane];
}

extern "C" void kernel_launch(void* const* d_in, const int* in_sizes, int n_in,
                              void* d_out, int out_size, void* d_ws, size_t ws_size,
                              hipStream_t stream) {
  const float* x   =(const float*)d_in[0];
  const float* d0  =(const float*)d_in[1];
  const float* w1  =(const float*)d_in[2];
  const float* b1  =(const float*)d_in[3];
  const float* dir1=(const float*)d_in[4];
  const float* g1  =(const float*)d_in[5];
  const float* bb1 =(const float*)d_in[6];
  const float* w2  =(const float*)d_in[7];
  const float* b2  =(const float*)d_in[8];
  const float* dir2=(const float*)d_in[9];
  const float* g2  =(const float*)d_in[10];
  const float* bb2 =(const float*)d_in[11];
  const float* w3  =(const float*)d_in[12];
  const float* b3  =(const float*)d_in[13];
  const float* dir3=(const float*)d_in[14];
  const float* g3  =(const float*)d_in[15];
  const float* bb3 =(const float*)d_in[16];
  const float* w4  =(const float*)d_in[17];
  const float* b4  =(const float*)d_in[18];
  const float* dir4=(const float*)d_in[19];
  const int* perm1 =(const int*)d_in[20];
  const int* perm2 =(const int*)d_in[21];
  float* out=(float*)d_out;

  float* w=(float*)d_ws;
  size_t off=0;
  auto alloc=[&](size_t n){ float* p=w+off; off+=n; return p; };
  float* cn0 =alloc(2688);
  float* cn1 =alloc(2688);
  float* cn2 =alloc(5376);
  float* cn3 =alloc(5376);
  float* cn4 =alloc(10752);
  float* dirnx =alloc((size_t)BNUM*V0*30);
  float* dirnv1=alloc((size_t)BNUM*V1N*30);
  float* dirnv2=alloc((size_t)BNUM*V2N*30);
  float* fm0 =alloc((size_t)BNUM*V0*128);
  float* cent=alloc((size_t)BNUM*V0*128);
  unsigned short* supb=(unsigned short*)alloc((size_t)BNUM*V0*896/2);
  float* fm1r=alloc((size_t)BNUM*V0*128);
  float* fm1 =alloc((size_t)BNUM*V0*128);
  float* f1  =alloc((size_t)BNUM*V1N*128);
  float* v1  =alloc((size_t)BNUM*V1N*3);
  float* fm2r=alloc((size_t)BNUM*V1N*256);
  float* fm2 =alloc((size_t)BNUM*V1N*256);
  float* fm3r=alloc((size_t)BNUM*V1N*256);
  float* fm3 =alloc((size_t)BNUM*V1N*256);
  float* f2  =alloc((size_t)BNUM*V2N*256);
  float* v2  =alloc((size_t)BNUM*V2N*3);
  float* fm4 =alloc((size_t)BNUM*V2N*512);
  float* stats=alloc(1280);
  int* idx10x =(int*)alloc((size_t)BNUM*V0*10);
  int* idx10v1=(int*)alloc((size_t)BNUM*V1N*10);
  int* idx10v2=(int*)alloc((size_t)BNUM*V2N*10);

  colnorm_all_k<<<dim3(35),256,0,stream>>>(d0,dir1,dir2,dir3,dir4,cn0,cn1,cn2,cn3,cn4,stats);

  // knn10 on x
  knn10_k<V0,1024,4><<<dim3(V0/16,BNUM),1024,0,stream>>>(x, idx10x, dirnx);
  // fm0 = silu(conv_surface) -> fm0 scratch + out[:, :128]
  conv_surf_k<4><<<dim3(V0/4,BNUM),256,0,stream>>>(dirnx, cn0, fm0, out);

  // layer 1 (C=128): GEMM 8192x1024x128
  gemm_mfma_k<<<dim3(1024/128,(BNUM*V0)/128),256,0,stream>>>(fm0, w1, b1, cent, supb, BNUM*V0, 1024, 128, 128);
  conv_agg_k<128,32,8><<<dim3(V0/8,BNUM),256,0,stream>>>(cent, supb, V0, dirnx, idx10x, cn1, fm1r, stats);
  bn_silu_k<<<dim3((BNUM*V0*128/4)/256),256,0,stream>>>(fm1r, stats, 1.0f/(BNUM*V0), 128, g1, bb1, fm1, BNUM*V0*128/4, out+128, 7);

  // pool (first-4 of idx10x at perm1) + v1 gather
  pool_gather_k<128,8><<<dim3(V1N/8,BNUM),256,0,stream>>>(fm1, V0, idx10x, perm1, x, f1, v1, V1N);

  // knn10 on v1
  knn10_k<V1N,256,6><<<dim3(V1N/4,BNUM),256,0,stream>>>(v1, idx10v1, dirnv1);

  // layer 2 (C=256): GEMM 2048x2048x128
  gemm_mfma_k<<<dim3(2048/128,(BNUM*V1N)/128),256,0,stream>>>(f1, w2, b2, cent, supb, BNUM*V1N, 2048, 128, 256);
  conv_agg_k<256,64,4><<<dim3(V1N/4,BNUM),256,0,stream>>>(cent, supb, V1N, dirnv1, idx10v1, cn2, fm2r, stats+256);
  bn_silu_k<<<dim3((BNUM*V1N*256/4)/256),256,0,stream>>>(fm2r, stats+256, 1.0f/(BNUM*V1N), 256, g2, bb2, fm2, BNUM*V1N*256/4, nullptr, 8);

  // layer 3 (C=256): GEMM 2048x2048x256
  gemm_mfma_k<<<dim3(2048/128,(BNUM*V1N)/128),256,0,stream>>>(fm2, w3, b3, cent, supb, BNUM*V1N, 2048, 256, 256);
  conv_agg_k<256,64,4><<<dim3(V1N/4,BNUM),256,0,stream>>>(cent, supb, V1N, dirnv1, idx10v1, cn3, fm3r, stats+768);
  bn_silu_k<<<dim3((BNUM*V1N*256/4)/256),256,0,stream>>>(fm3r, stats+768, 1.0f/(BNUM*V1N), 256, g3, bb3, fm3, BNUM*V1N*256/4, nullptr, 8);

  // pool (first-4 of idx10v1 at perm2) + v2 gather
  pool_gather_k<256,4><<<dim3(V2N/4,BNUM),256,0,stream>>>(fm3, V1N, idx10v1, perm2, v1, f2, v2, V2N);

  // knn10 on v2
  knn10_k<V2N,256,6><<<dim3(V2N/4,BNUM),256,0,stream>>>(v2, idx10v2, dirnv2);

  // layer 4 (C=512): GEMM 512x4096x256, no bn/silu
  gemm_mfma_k<<<dim3(4096/128,(BNUM*V2N)/128),256,0,stream>>>(f2, w4, b4, cent, supb, BNUM*V2N, 4096, 256, 512);
  conv_agg_k<512,128,2><<<dim3(V2N/2,BNUM),256,0,stream>>>(cent, supb, V2N, dirnv2, idx10v2, cn4, fm4, nullptr);

  // fused nearest + upsample concat
  nearest_concat_k<<<dim3(V0/8,BNUM),512,0,stream>>>(v1, v2, x, fm2, fm3, fm4, out);
}